// Round 1
// baseline (1224.387 us; speedup 1.0000x reference)
//
#include <hip/hip_runtime.h>

#define NBATCH 64
#define SRCLEN 2048
#define DIMK 1024
#define MROWS (NBATCH * SRCLEN) /* 131072 */
#define NNB 4                   /* n-blocks of 256 */

typedef __attribute__((ext_vector_type(4))) float f32x4;
typedef __attribute__((ext_vector_type(8))) short bf16x8;

#define AS_GLOBAL __attribute__((address_space(1)))
#define AS_LDS __attribute__((address_space(3)))

#define SWAIT8() asm volatile("s_waitcnt vmcnt(8)" ::: "memory")
#define SWAIT0() asm volatile("s_waitcnt vmcnt(0)" ::: "memory")
#define SBAR()                              \
  do {                                      \
    __builtin_amdgcn_sched_barrier(0);      \
    __builtin_amdgcn_s_barrier();           \
    __builtin_amdgcn_sched_barrier(0);      \
  } while (0)

__device__ __forceinline__ int cvt_pk_bf16(float a, float b) {
#if __has_builtin(__builtin_amdgcn_cvt_pk_bf16_f32)
  auto p = __builtin_amdgcn_cvt_pk_bf16_f32(a, b);
  return __builtin_bit_cast(int, p);
#else
  unsigned ua = __float_as_uint(a), ub = __float_as_uint(b);
  ua = (ua + 0x7fffu + ((ua >> 16) & 1u)) >> 16;
  ub = (ub + 0x7fffu + ((ub >> 16) & 1u)) & 0xffff0000u;
  return (int)(ua | ub);
#endif
}

__device__ __forceinline__ float fast_tanh(float x) {
#if __has_builtin(__builtin_amdgcn_exp2f) && __has_builtin(__builtin_amdgcn_rcpf)
  float e = __builtin_amdgcn_exp2f(x * 2.885390081777927f);
  return 1.0f - 2.0f * __builtin_amdgcn_rcpf(e + 1.0f);
#else
  float cx = fminf(15.f, fmaxf(-15.f, x));
  float e = __expf(2.0f * cx);
  return (e - 1.0f) / (e + 1.0f);
#endif
}

// ---------------- K0a: W_context fp32 -> bf16 (row-major [n][k]) ----------------
__global__ __launch_bounds__(256) void cvt_wc_kernel(const float* __restrict__ W,
                                                     unsigned short* __restrict__ Wb) {
  int i = (blockIdx.x * 256 + threadIdx.x) * 4;
  f32x4 x = *(const f32x4*)(W + i);
  int2 o;
  o.x = cvt_pk_bf16(x[0], x[1]);
  o.y = cvt_pk_bf16(x[2], x[3]);
  *(int2*)(Wb + i) = o;
}

// ---------------- K0b: bias[b][n] = src@Wq^T + cond@Wcd^T + bq ----------------
__global__ __launch_bounds__(256) void bias_kernel(
    const float* __restrict__ src, const float* __restrict__ cond,
    const float* __restrict__ Wq, const float* __restrict__ bq,
    const float* __restrict__ Wcd, float* __restrict__ biasOut) {
  const int b = blockIdx.y, nb = blockIdx.x, tid = threadIdx.x;
  const int w = tid >> 6, lane = tid & 63;
  __shared__ float sl[1024], cl[1024];
  *(f32x4*)(sl + (tid << 2)) = *(const f32x4*)(src + (b << 10) + (tid << 2));
  *(f32x4*)(cl + (tid << 2)) = *(const f32x4*)(cond + (b << 10) + (tid << 2));
  __syncthreads();
  f32x4 s4[4], c4[4];
#pragma unroll
  for (int u = 0; u < 4; ++u) {
    s4[u] = *(const f32x4*)(sl + (lane << 4) + (u << 2));
    c4[u] = *(const f32x4*)(cl + (lane << 4) + (u << 2));
  }
  for (int it = 0; it < 32; ++it) {
    const int n = (nb << 7) + (w << 5) + it;
    const float* wq = Wq + (size_t)n * DIMK + (lane << 4);
    const float* wc = Wcd + (size_t)n * DIMK + (lane << 4);
    float a = 0.f;
#pragma unroll
    for (int u = 0; u < 4; ++u) {
      f32x4 q4 = *(const f32x4*)(wq + (u << 2));
      f32x4 w4 = *(const f32x4*)(wc + (u << 2));
      a += q4[0] * s4[u][0] + q4[1] * s4[u][1] + q4[2] * s4[u][2] + q4[3] * s4[u][3];
      a += w4[0] * c4[u][0] + w4[1] * c4[u][1] + w4[2] * c4[u][2] + w4[3] * c4[u][3];
    }
#pragma unroll
    for (int xm = 1; xm < 64; xm <<= 1) a += __shfl_xor(a, xm, 64);
    if (lane == 0) biasOut[(b << 10) + n] = a + bq[n];
  }
}

// ---------------- KB: fused GEMM + tanh + v-dot -> align partials ----------------
// Block tile 128m x 256n, 4 waves (2x2) each 64m x 128n, 16x16x32 bf16 MFMA.
// Pipeline: BK=32 double-buffered stages, counted s_waitcnt vmcnt(8) (never drain
// to 0 in the main loop), raw s_barrier.  XCD-swizzled 1-D grid so the 4 n-blocks
// sharing an A panel land on the same XCD's L2.
// LDS swizzles (2-way max = free):
//   A [128][32] f32, 8x16B chunks/row:  stored chunk = c ^ (row & 7)
//   B [256][32] bf16, 4x16B chunks/row: stored chunk = c ^ ((row >> 1) & 3)
__device__ __forceinline__ void gemm_stage(const float* const aSrc[4],
                                           const unsigned short* const bSrc[4], int kt,
                                           float* Asd, unsigned short* Bsd, int w) {
#pragma unroll
  for (int r = 0; r < 4; ++r) {
    int q = (w << 2) + r;
    __builtin_amdgcn_global_load_lds((const AS_GLOBAL unsigned*)(aSrc[r] + (kt << 5)),
                                     (AS_LDS unsigned*)(Asd + (q << 8)), 16, 0, 0);
    __builtin_amdgcn_global_load_lds((const AS_GLOBAL unsigned*)(bSrc[r] + (kt << 5)),
                                     (AS_LDS unsigned*)(Bsd + (q << 9)), 16, 0, 0);
  }
}

__device__ __forceinline__ void gemm_compute(const float* Asd, const unsigned short* Bsd,
                                             f32x4 acc[4][8], int wm, int wn, int lr,
                                             int quad) {
  bf16x8 af[4];
  const int p0 = (quad << 1) ^ (lr & 7);       // A stored chunk for logical chunk quad*2
  const int sc = quad ^ ((lr >> 1) & 3);       // B stored chunk for logical chunk quad
#pragma unroll
  for (int i = 0; i < 4; ++i) {
    int row = (wm << 6) + (i << 4) + lr;
    f32x4 lo = *(const f32x4*)(Asd + (row << 5) + (p0 << 2));
    f32x4 hi = *(const f32x4*)(Asd + (row << 5) + ((p0 ^ 1) << 2));
    union { int i4[4]; bf16x8 v8; } u;
    u.i4[0] = cvt_pk_bf16(lo[0], lo[1]);
    u.i4[1] = cvt_pk_bf16(lo[2], lo[3]);
    u.i4[2] = cvt_pk_bf16(hi[0], hi[1]);
    u.i4[3] = cvt_pk_bf16(hi[2], hi[3]);
    af[i] = u.v8;
  }
#pragma unroll
  for (int j = 0; j < 8; ++j) {
    int row = (wn << 7) + (j << 4) + lr;
    bf16x8 bfv = *(const bf16x8*)(Bsd + (row << 5) + (sc << 3));
#pragma unroll
    for (int i = 0; i < 4; ++i)
      acc[i][j] = __builtin_amdgcn_mfma_f32_16x16x32_bf16(af[i], bfv, acc[i][j], 0, 0, 0);
  }
}

__global__ __launch_bounds__(256, 2) void gemm_align_kernel(
    const float* __restrict__ mb, const unsigned short* __restrict__ Wc,
    const float* __restrict__ bias, const float* __restrict__ v,
    float* __restrict__ alignP) {
  __shared__ __align__(16) float As[2][128 * 32];           // 2 x 16 KiB
  __shared__ __align__(16) unsigned short Bs[2][256 * 32];  // 2 x 16 KiB
  __shared__ float red[2][128];

  const int tid = threadIdx.x;
  const int lane = tid & 63;
  const int w = tid >> 6;
  const int wm = w & 1, wn = w >> 1;
  const int lr = lane & 15, quad = lane >> 4;

  // XCD-aware bijective swizzle: 4096 wgs, 8 XCDs, 512 contiguous wgids per XCD.
  // Each XCD owns m-tiles [xcd*128, xcd*128+128), all 4 n-blocks of an m-tile adjacent.
  const int Lb = blockIdx.x;
  const int wg = ((Lb & 7) << 9) | (Lb >> 3);
  const int mt = wg >> 2;
  const int nb = wg & 3;
  const int m0 = mt << 7;
  const int n0 = nb << 8;

  // Per-thread staging sources (advance by 32 elements per stage).
  // A instr q covers rows q*8..q*8+7 (row = q*8 + lane>>3), chunk (lane&7)^(lane>>3).
  // B instr q covers rows q*16..q*16+15 (row = q*16 + lane>>2), chunk (lane&3)^((lane>>3)&3).
  const float* aSrc[4];
  const unsigned short* bSrc[4];
#pragma unroll
  for (int r = 0; r < 4; ++r) {
    int q = (w << 2) + r;
    aSrc[r] = mb + (size_t)(m0 + (q << 3) + (lane >> 3)) * DIMK +
              (((lane & 7) ^ (lane >> 3)) << 2);
    bSrc[r] = Wc + (size_t)(n0 + (q << 4) + (lane >> 2)) * DIMK +
              (((lane & 3) ^ ((lane >> 3) & 3)) << 3);
  }

  float* A0 = &As[0][0];
  float* A1 = &As[1][0];
  unsigned short* B0 = &Bs[0][0];
  unsigned short* B1 = &Bs[1][0];

  f32x4 acc[4][8] = {};

  gemm_stage(aSrc, bSrc, 0, A0, B0, w);
#pragma unroll 1
  for (int kt = 0; kt < 30; kt += 2) {
    gemm_stage(aSrc, bSrc, kt + 1, A1, B1, w);
    SWAIT8();  // stage kt landed; stage kt+1 stays in flight through compute
    SBAR();
    gemm_compute(A0, B0, acc, wm, wn, lr, quad);
    SBAR();
    gemm_stage(aSrc, bSrc, kt + 2, A0, B0, w);
    SWAIT8();
    SBAR();
    gemm_compute(A1, B1, acc, wm, wn, lr, quad);
    SBAR();
  }
  gemm_stage(aSrc, bSrc, 31, A1, B1, w);
  SWAIT8();
  SBAR();
  gemm_compute(A0, B0, acc, wm, wn, lr, quad);  // stage 30
  SBAR();
  SWAIT0();  // epilogue of pipeline: drain last stage
  SBAR();
  gemm_compute(A1, B1, acc, wm, wn, lr, quad);  // stage 31

  // Epilogue: t = tanh(acc + bias[b][n]); partial_align[m] += t * v[n]
  const int b = mt >> 4;  // 16 m-tiles per batch -> uniform per block
  float rowsum[4][4] = {};
#pragma unroll
  for (int j = 0; j < 8; ++j) {
    int n = n0 + (wn << 7) + (j << 4) + lr;  // C/D col = lane&15
    float bn = bias[(b << 10) + n];
    float vn = v[n];
#pragma unroll
    for (int i = 0; i < 4; ++i)
#pragma unroll
      for (int rg = 0; rg < 4; ++rg) {
        float t = fast_tanh(acc[i][j][rg] + bn);
        rowsum[i][rg] = fmaf(t, vn, rowsum[i][rg]);
      }
  }
#pragma unroll
  for (int xm = 1; xm < 16; xm <<= 1)
#pragma unroll
    for (int i = 0; i < 4; ++i)
#pragma unroll
      for (int rg = 0; rg < 4; ++rg)
        rowsum[i][rg] += __shfl_xor(rowsum[i][rg], xm, 64);
  if (lr == 0) {
#pragma unroll
    for (int i = 0; i < 4; ++i)
#pragma unroll
      for (int rg = 0; rg < 4; ++rg)
        red[wn][(wm << 6) + (i << 4) + (quad << 2) + rg] = rowsum[i][rg];
  }
  __syncthreads();
  if (tid < 128)
    alignP[(size_t)nb * MROWS + m0 + tid] = red[0][tid] + red[1][tid];
}

// ---------------- KC: softmax over s per batch; writes output 1 ----------------
__global__ __launch_bounds__(256) void softmax_kernel(const float* __restrict__ alignP,
                                                      float* __restrict__ outA) {
  const int b = blockIdx.x, tid = threadIdx.x;
  float loc[8];
  float mx = -3.0e38f;
#pragma unroll
  for (int r = 0; r < 8; ++r) {
    int s = (r << 8) + tid;
    float a = 0.f;
#pragma unroll
    for (int q = 0; q < NNB; ++q) a += alignP[(size_t)q * MROWS + (b << 11) + s];
    loc[r] = a;
    mx = fmaxf(mx, a);
  }
#pragma unroll
  for (int o = 32; o > 0; o >>= 1) mx = fmaxf(mx, __shfl_xor(mx, o, 64));
  __shared__ float sred[8];
  if ((tid & 63) == 0) sred[tid >> 6] = mx;
  __syncthreads();
  mx = fmaxf(fmaxf(sred[0], sred[1]), fmaxf(sred[2], sred[3]));
  float sum = 0.f;
#pragma unroll
  for (int r = 0; r < 8; ++r) {
    loc[r] = __expf(loc[r] - mx);
    sum += loc[r];
  }
#pragma unroll
  for (int o = 32; o > 0; o >>= 1) sum += __shfl_xor(sum, o, 64);
  __syncthreads();
  if ((tid & 63) == 0) sred[4 + (tid >> 6)] = sum;
  __syncthreads();
  sum = sred[4] + sred[5] + sred[6] + sred[7];
  float inv = 1.0f / sum;
#pragma unroll
  for (int r = 0; r < 8; ++r) outA[(b << 11) + (r << 8) + tid] = loc[r] * inv;
}

// ---------------- KD: context partials c_chunk[b][d] = sum_s w*h ----------------
__global__ __launch_bounds__(256) void ctx_partial_kernel(const float* __restrict__ mb,
                                                          const float* __restrict__ wgt,
                                                          float* __restrict__ cP) {
  const int chunk = blockIdx.x, b = blockIdx.y, tid = threadIdx.x;
  __shared__ float wl[64];
  if (tid < 64) wl[tid] = wgt[(b << 11) + (chunk << 6) + tid];
  __syncthreads();
  const float* base = mb + ((size_t)(b << 11) + (chunk << 6)) * DIMK + (tid << 2);
  f32x4 a = {0.f, 0.f, 0.f, 0.f};
#pragma unroll 4
  for (int s = 0; s < 64; ++s) {
    f32x4 m4 = *(const f32x4*)(base + (size_t)s * DIMK);
    a += m4 * wl[s];
  }
  *(f32x4*)(cP + ((size_t)((chunk << 6) + b) << 10) + (tid << 2)) = a;
}

// ---------------- KE: reduce 32 chunks -> c (output 0) ----------------
__global__ __launch_bounds__(256) void ctx_reduce_kernel(const float* __restrict__ cP,
                                                         float* __restrict__ out) {
  int idx = blockIdx.x * 256 + threadIdx.x;
  float s = 0.f;
#pragma unroll
  for (int c = 0; c < 32; ++c) s += cP[(size_t)(c << 16) + idx];
  out[idx] = s;
}

extern "C" void kernel_launch(void* const* d_in, const int* in_sizes, int n_in,
                              void* d_out, int out_size, void* d_ws, size_t ws_size,
                              hipStream_t stream) {
  const float* source = (const float*)d_in[0];
  const float* mb = (const float*)d_in[1];
  const float* cond = (const float*)d_in[2];
  const float* Wq = (const float*)d_in[3];
  const float* bq = (const float*)d_in[4];
  const float* Wc = (const float*)d_in[5];
  const float* Wcd = (const float*)d_in[6];
  const float* v = (const float*)d_in[7];
  float* out = (float*)d_out;

  // ws: Wc_bf16 2 MiB | bias 256 KiB | alignP 2 MiB | cP 8 MiB
  char* ws = (char*)d_ws;
  unsigned short* Wc_bf = (unsigned short*)ws;
  float* bias = (float*)(ws + (2u << 20));
  float* alignP = (float*)(ws + (2u << 20) + (256u << 10));
  float* cP = (float*)(ws + (4u << 20) + (256u << 10));

  cvt_wc_kernel<<<1024, 256, 0, stream>>>(Wc, Wc_bf);
  bias_kernel<<<dim3(8, 64), 256, 0, stream>>>(source, cond, Wq, bq, Wcd, bias);
  gemm_align_kernel<<<4096, 256, 0, stream>>>(mb, Wc_bf, bias, v, alignP);
  softmax_kernel<<<64, 256, 0, stream>>>(alignP, out + NBATCH * DIMK);
  ctx_partial_kernel<<<dim3(32, 64), 256, 0, stream>>>(mb, out + NBATCH * DIMK, cP);
  ctx_reduce_kernel<<<256, 256, 0, stream>>>(cP, out);
}